// Round 1
// 403.897 us; speedup vs baseline: 1.0391x; 1.0391x over previous
//
#include <hip/hip_runtime.h>
#include <cstddef>

// Vanilla tanh-RNN: B=4096, T=2048, I=4, H=20, then Linear(20->4) on h_last.
//
// Round-7: packed dual-FP32 (v_pk_fma_f32, VOP3P) step.
//
// R3-R6 law: wall ~ per-SIMD VALU inst count; R6 = 58 insts/step at ~5.8
// cyc/inst avg, 38 of them DPP-fmacs. Hypothesis: DPP-modified VALU carries
// a per-inst premium (fits 38x8 + 20x2.5 ~ 346 cyc; also explains R5's
// zero cross-wave overlap via a shared slow DPP path).
//
// Change: each rotation r feeds BOTH unit-chains (wA[r], wB[r]) with the
// same rotated hA. Fuse the pair into ONE v_pk_fma_f32:
//     v_mov_b32_dpp t, hA row_ror:r          (only DPP inst)
//     v_pk_fma_f32 {aA,aB} += {wA,wB} x {t,t}  (op_sel_hi:[1,0,1] bcasts t.lo)
// DPP insts 38 -> 19; xi packs 8 -> 4 (op_sel selects xv.x/y/z/w from the
// natural ds_read pairs); combine 2 -> 1. Total 53 VALU/step (was 58).
// Arithmetic order is bit-identical to R6 (same chains, same term order).
//
// Implementation: one asm block per step. Fixed VGPRs v42-v51 are pure
// intra-block scratch (clobbered; nothing lives in them across blocks).
// h state stays in compiler-allocated "+v" operands; weight pairs are f32x2
// "v" operands (even-aligned VReg_64 on gfx90a+ targets). Hi halves of the
// t scratch pairs (v43/v45) are never read: op_sel_hi[1]=0 selects word0.
//
// DPP hazard (VALU-write -> DPP-read needs 2 insts): next block's first
// mov_dpp reading hA is 6 insts after the v_fma that writes hA. Quad movs
// read hB written ~40 insts prior.
//
// x staging: unchanged from R4/R6 (wave-local LDS double buffer, 3-step
// register lookahead, zero barriers, intra-wave DS program order).

typedef float f32x2 __attribute__((ext_vector_type(2)));
typedef float f32x4 __attribute__((ext_vector_type(4)));

constexpr int Tn   = 2048;
constexpr int Hn   = 20;
constexpr int EPB  = 16;   // elements per 256-thread block
constexpr int SB   = 16;   // steps per staging block
constexpr int NBLK = Tn / SB;

__global__ __launch_bounds__(256, 1) void rnn_fwd(
    const float* __restrict__ x,     // [B, T, 4]
    const float* __restrict__ h0,    // [B, 20]
    const float* __restrict__ W_ih,  // [20, 4]
    const float* __restrict__ W_hh,  // [20, 20]
    const float* __restrict__ b_ih,  // [20]
    const float* __restrict__ b_hh,  // [20]
    const float* __restrict__ fc_w,  // [4, 20]
    const float* __restrict__ fc_b,  // [4]
    float* __restrict__ out)         // [B, 4]
{
    __shared__ __align__(16) f32x4 xlds[2][EPB][SB + 1];
    __shared__ float hsh[EPB][24];

    const int tid = threadIdx.x;
    const int j   = tid & 15;             // lane within row = A-target unit
    const int e   = tid >> 4;             // element slot in block (0..15)
    const int b   = blockIdx.x * EPB + e;
    const int uB  = 16 + (j & 3);         // B-target unit

    // Weights pre-scaled by 2*log2(e) so tanh = 1 - 2*rcp(exp2(s)+1).
    const float S = 2.88539008177792681472f;

    // Pair weights: lo half = A-chain (unit j), hi half = B-chain (unit uB).
    f32x2 w2[16];
#pragma unroll
    for (int r = 0; r < 16; ++r) {
        const int k = (j - r) & 15;       // unit delivered by row_ror:r
        w2[r] = f32x2{S * W_hh[j * Hn + k], S * W_hh[uB * Hn + k]};
    }
    f32x2 wq2[4], xiw[4];
#pragma unroll
    for (int c = 0; c < 4; ++c) {
        wq2[c] = f32x2{S * W_hh[j * Hn + 16 + c], S * W_hh[uB * Hn + 16 + c]};
        xiw[c] = f32x2{S * W_ih[j * 4 + c],       S * W_ih[uB * 4 + c]};
    }
    f32x2 bias2 = f32x2{S * (b_ih[j] + b_hh[j]), S * (b_ih[uB] + b_hh[uB])};

    // ---- initial state ----
    float hA = h0[b * Hn + j];
    float hB = h0[b * Hn + uB];           // h_{16+(j&3)}: quad-replicated by layout

    const f32x4* __restrict__ xp =
        reinterpret_cast<const f32x4*>(x) + (size_t)b * Tn;

#define DPPM " row_mask:0xf bank_mask:0xf\n\t"
#define PKB  " op_sel:[0,0,0] op_sel_hi:[1,0,1]\n\t"   /* bcast S1 word0 */

#define STEP(XV) do {                                                         \
    f32x2 xa_ = __builtin_shufflevector((XV), (XV), 0, 1);                    \
    f32x2 xb_ = __builtin_shufflevector((XV), (XV), 2, 3);                    \
    asm volatile(                                                             \
  /* xi + bias: accP=v[46:47]={a0,c0}, accQ=v[48:49]={a1,c1} */               \
  "v_pk_fma_f32 v[46:47], %[x0], %[xa], %[b2]" PKB                            \
  "v_pk_mul_f32 v[48:49], %[x1], %[xa] op_sel:[0,1] op_sel_hi:[1,1]\n\t"      \
  "v_pk_fma_f32 v[46:47], %[x2], %[xb], v[46:47]" PKB                         \
  "v_pk_fma_f32 v[48:49], %[x3], %[xb], v[48:49] op_sel:[0,1,0] op_sel_hi:[1,1,1]\n\t" \
  /* seed t0.lo with hA for the r=0 broadcast */                              \
  "v_mov_b32 v42, %[hA]\n\t"                                                  \
  /* rotations r=0..15, quads c=0..3; t alternates v42/v44 */                 \
  "v_mov_b32_dpp v44, %[hA] row_ror:1"  DPPM                                  \
  "v_pk_fma_f32 v[46:47], %[w0], v[42:43], v[46:47]" PKB                      \
  "v_mov_b32_dpp v42, %[hA] row_ror:2"  DPPM                                  \
  "v_pk_fma_f32 v[48:49], %[w1], v[44:45], v[48:49]" PKB                      \
  "v_mov_b32_dpp v44, %[hA] row_ror:3"  DPPM                                  \
  "v_pk_fma_f32 v[46:47], %[w2], v[42:43], v[46:47]" PKB                      \
  "v_mov_b32_dpp v42, %[hA] row_ror:4"  DPPM                                  \
  "v_pk_fma_f32 v[48:49], %[w3], v[44:45], v[48:49]" PKB                      \
  "v_mov_b32_dpp v44, %[hA] row_ror:5"  DPPM                                  \
  "v_pk_fma_f32 v[46:47], %[w4], v[42:43], v[46:47]" PKB                      \
  "v_mov_b32_dpp v42, %[hA] row_ror:6"  DPPM                                  \
  "v_pk_fma_f32 v[48:49], %[w5], v[44:45], v[48:49]" PKB                      \
  "v_mov_b32_dpp v44, %[hA] row_ror:7"  DPPM                                  \
  "v_pk_fma_f32 v[46:47], %[w6], v[42:43], v[46:47]" PKB                      \
  "v_mov_b32_dpp v42, %[hA] row_ror:8"  DPPM                                  \
  "v_pk_fma_f32 v[48:49], %[w7], v[44:45], v[48:49]" PKB                      \
  "v_mov_b32_dpp v44, %[hA] row_ror:9"  DPPM                                  \
  "v_pk_fma_f32 v[46:47], %[w8], v[42:43], v[46:47]" PKB                      \
  "v_mov_b32_dpp v42, %[hA] row_ror:10" DPPM                                  \
  "v_pk_fma_f32 v[48:49], %[w9], v[44:45], v[48:49]" PKB                      \
  "v_mov_b32_dpp v44, %[hA] row_ror:11" DPPM                                  \
  "v_pk_fma_f32 v[46:47], %[w10], v[42:43], v[46:47]" PKB                     \
  "v_mov_b32_dpp v42, %[hA] row_ror:12" DPPM                                  \
  "v_pk_fma_f32 v[48:49], %[w11], v[44:45], v[48:49]" PKB                     \
  "v_mov_b32_dpp v44, %[hA] row_ror:13" DPPM                                  \
  "v_pk_fma_f32 v[46:47], %[w12], v[42:43], v[46:47]" PKB                     \
  "v_mov_b32_dpp v42, %[hA] row_ror:14" DPPM                                  \
  "v_pk_fma_f32 v[48:49], %[w13], v[44:45], v[48:49]" PKB                     \
  "v_mov_b32_dpp v44, %[hA] row_ror:15" DPPM                                  \
  "v_pk_fma_f32 v[46:47], %[w14], v[42:43], v[46:47]" PKB                     \
  "v_mov_b32_dpp v42, %[hB] quad_perm:[0,0,0,0]" DPPM                         \
  "v_pk_fma_f32 v[48:49], %[w15], v[44:45], v[48:49]" PKB                     \
  "v_mov_b32_dpp v44, %[hB] quad_perm:[1,1,1,1]" DPPM                         \
  "v_pk_fma_f32 v[46:47], %[q0], v[42:43], v[46:47]" PKB                      \
  "v_mov_b32_dpp v42, %[hB] quad_perm:[2,2,2,2]" DPPM                         \
  "v_pk_fma_f32 v[48:49], %[q1], v[44:45], v[48:49]" PKB                      \
  "v_mov_b32_dpp v44, %[hB] quad_perm:[3,3,3,3]" DPPM                         \
  "v_pk_fma_f32 v[46:47], %[q2], v[42:43], v[46:47]" PKB                      \
  "v_pk_fma_f32 v[48:49], %[q3], v[44:45], v[48:49]" PKB                      \
  /* combine + tanh (weights pre-scaled into exp2 domain) */                  \
  "v_pk_add_f32 v[46:47], v[46:47], v[48:49]\n\t"                             \
  "v_exp_f32 v50, v46\n\t"                                                    \
  "v_exp_f32 v51, v47\n\t"                                                    \
  "v_add_f32 v50, 1.0, v50\n\t"                                               \
  "v_add_f32 v51, 1.0, v51\n\t"                                               \
  "v_rcp_f32 v50, v50\n\t"                                                    \
  "v_rcp_f32 v51, v51\n\t"                                                    \
  "v_fma_f32 %[hA], v50, -2.0, 1.0\n\t"                                       \
  "v_fma_f32 %[hB], v51, -2.0, 1.0"                                           \
  : [hA] "+v"(hA), [hB] "+v"(hB)                                              \
  : [xa] "v"(xa_), [xb] "v"(xb_),                                             \
    [w0] "v"(w2[0]),   [w1] "v"(w2[1]),   [w2] "v"(w2[2]),   [w3] "v"(w2[3]), \
    [w4] "v"(w2[4]),   [w5] "v"(w2[5]),   [w6] "v"(w2[6]),   [w7] "v"(w2[7]), \
    [w8] "v"(w2[8]),   [w9] "v"(w2[9]),   [w10] "v"(w2[10]), [w11] "v"(w2[11]),\
    [w12] "v"(w2[12]), [w13] "v"(w2[13]), [w14] "v"(w2[14]), [w15] "v"(w2[15]),\
    [q0] "v"(wq2[0]),  [q1] "v"(wq2[1]),  [q2] "v"(wq2[2]),  [q3] "v"(wq2[3]),\
    [x0] "v"(xiw[0]),  [x1] "v"(xiw[1]),  [x2] "v"(xiw[2]),  [x3] "v"(xiw[3]),\
    [b2] "v"(bias2)                                                           \
  : "v42","v43","v44","v45","v46","v47","v48","v49","v50","v51");             \
} while (0)

    // ---- prologue: stage block 0, prime 3-deep queue ----
    xlds[0][e][j] = xp[j];                // lane j -> row j (coalesced)
    f32x4 q0 = xlds[0][e][0];
    f32x4 q1 = xlds[0][e][1];
    f32x4 q2 = xlds[0][e][2];

    int cur = 0;
#pragma unroll 1
    for (int k = 0; k < NBLK; ++k) {
        const int kn = (k + 1 < NBLK) ? (k + 1) : (NBLK - 1);  // tail reload
        f32x4 xr = xp[kn * SB + j];       // global load at block TOP (~13 steps slack)
        const int nxt = cur ^ 1;
#pragma unroll
        for (int s = 0; s < SB - 3; ++s) {                     // s = 0..12
            f32x4 xv = q0; q0 = q1; q1 = q2;
            q2 = xlds[cur][e][s + 3];     // 3-step LDS lookahead
            STEP(xv);
        }
        xlds[nxt][e][j] = xr;             // prior reads of nxt already issued
        { f32x4 xv = q0; q0 = q1; q1 = q2; q2 = xlds[nxt][e][0]; STEP(xv); }
        { f32x4 xv = q0; q0 = q1; q1 = q2; q2 = xlds[nxt][e][1]; STEP(xv); }
        { f32x4 xv = q0; q0 = q1; q1 = q2; q2 = xlds[nxt][e][2]; STEP(xv); }
        cur = nxt;
    }
#undef STEP
#undef PKB
#undef DPPM

    // ---- epilogue: out[b][m] = fc_b[m] + sum_k h[k] * fc_w[m][k] ----
    hsh[e][j] = hA;                       // units 0..15
    if (j < 4) hsh[e][16 + j] = hB;       // lane j holds unit 16+j
    if (j < 4) {
        float o = fc_b[j];
#pragma unroll
        for (int kk = 0; kk < Hn; ++kk)
            o = __builtin_fmaf(hsh[e][kk], fc_w[j * Hn + kk], o);
        out[b * 4 + j] = o;
    }
}

extern "C" void kernel_launch(void* const* d_in, const int* in_sizes, int n_in,
                              void* d_out, int out_size, void* d_ws, size_t ws_size,
                              hipStream_t stream) {
    const float* x    = (const float*)d_in[0];
    const float* h0   = (const float*)d_in[1];
    const float* W_ih = (const float*)d_in[2];
    const float* W_hh = (const float*)d_in[3];
    const float* b_ih = (const float*)d_in[4];
    const float* b_hh = (const float*)d_in[5];
    const float* fc_w = (const float*)d_in[6];
    const float* fc_b = (const float*)d_in[7];
    float* out = (float*)d_out;

    // 4096 elements / 16 per block = 256 blocks = 1024 waves = 1 wave/SIMD.
    rnn_fwd<<<dim3(256), dim3(256), 0, stream>>>(x, h0, W_ih, W_hh, b_ih, b_hh,
                                                 fc_w, fc_b, out);
}

// Round 2
// 400.743 us; speedup vs baseline: 1.0472x; 1.0079x over previous
//
#include <hip/hip_runtime.h>
#include <cstddef>

// Vanilla tanh-RNN: B=4096, T=2048, I=4, H=20, then Linear(20->4) on h_last.
//
// Round-8: cross-step software pipelining of xi + 4 packed chains.
//
// Cost model from R6/R7 fit: DPP ~7.7 cyc, pk_f32 ~6.8, scalar VALU ~2.7,
// per-SIMD issue-serialized (R5: zero cross-wave overlap). VALUBusy=75% ->
// ~85 cyc/step of issue bubbles, concentrated in the serial tanh tail
// (pk_add->exp->add->rcp->fma) where R7 had nothing independent to issue.
//
// Change vs R7:
//  * xi(t+1) (h-independent) is computed INSIDE step t's tanh tail,
//    textually interleaved into the trans-op latency gaps. xi accumulators
//    xiP..xiS are cross-step state ("+v" f32x2 vars); queue re-phased so
//    q0 = xv(t+1) at step t (prologue computes xi(0) directly).
//  * 4 packed chains (P,Q,R,S), depth 6, 2-level pk_add combine.
//  * 3 rotating DPP t-buffers (v42/44/46): every pk_fma reads a mov_dpp
//    issued 3 insts earlier; first DPP read of hA is >=3 insts after its
//    write (DPP read-after-VALU-write hazard).
//  * Step split into two asm blocks (MAC / tail+xi) to stay under the
//    inline-asm operand limit; same MACs, reassociated (fp32 ~1e-6 jitter).
//
// Layout identical to R4-R7 (validated): 16 lanes/element, 4 elem/wave,
// 1024 waves = 1 wave/SIMD. Lane j holds h_j (hA) and h_{16+(j&3)} (hB,
// quad-replicated). row_ror:r delivers h_{(j-r)&15}; weights pre-permuted
// w2[r] = {W_hh[j][(j-r)&15], W_hh[uB][(j-r)&15]}, pre-scaled by
// 2*log2(e) so tanh = 1 - 2*rcp(exp2(s)+1).
//
// x staging: R3-R7 wave-local LDS double buffer, zero barriers (intra-wave
// DS program order), queue shifted one step earlier (q primes at x[1..3]).

typedef float f32x2 __attribute__((ext_vector_type(2)));
typedef float f32x4 __attribute__((ext_vector_type(4)));

constexpr int Tn   = 2048;
constexpr int Hn   = 20;
constexpr int EPB  = 16;   // elements per 256-thread block
constexpr int SB   = 16;   // steps per staging block
constexpr int NBLK = Tn / SB;

__global__ __launch_bounds__(256, 1) void rnn_fwd(
    const float* __restrict__ x,     // [B, T, 4]
    const float* __restrict__ h0,    // [B, 20]
    const float* __restrict__ W_ih,  // [20, 4]
    const float* __restrict__ W_hh,  // [20, 20]
    const float* __restrict__ b_ih,  // [20]
    const float* __restrict__ b_hh,  // [20]
    const float* __restrict__ fc_w,  // [4, 20]
    const float* __restrict__ fc_b,  // [4]
    float* __restrict__ out)         // [B, 4]
{
    __shared__ __align__(16) f32x4 xlds[2][EPB][SB + 1];
    __shared__ float hsh[EPB][24];

    const int tid = threadIdx.x;
    const int j   = tid & 15;             // lane within row = A-target unit
    const int e   = tid >> 4;             // element slot in block (0..15)
    const int b   = blockIdx.x * EPB + e;
    const int uB  = 16 + (j & 3);         // B-target unit

    const float S = 2.88539008177792681472f;  // 2/ln(2)

    // Pair weights: lo = A-chain (unit j), hi = B-chain (unit uB).
    f32x2 w2[16];
#pragma unroll
    for (int r = 0; r < 16; ++r) {
        const int k = (j - r) & 15;       // unit delivered by row_ror:r
        w2[r] = f32x2{S * W_hh[j * Hn + k], S * W_hh[uB * Hn + k]};
    }
    f32x2 wq2[4], xiw[4];
#pragma unroll
    for (int c = 0; c < 4; ++c) {
        wq2[c] = f32x2{S * W_hh[j * Hn + 16 + c], S * W_hh[uB * Hn + 16 + c]};
        xiw[c] = f32x2{S * W_ih[j * 4 + c],       S * W_ih[uB * 4 + c]};
    }
    f32x2 bias2 = f32x2{S * (b_ih[j] + b_hh[j]), S * (b_ih[uB] + b_hh[uB])};

    // ---- initial state ----
    float hA = h0[b * Hn + j];
    float hB = h0[b * Hn + uB];           // h_{16+(j&3)}: quad-replicated

    const f32x4* __restrict__ xp =
        reinterpret_cast<const f32x4*>(x) + (size_t)b * Tn;

#define DPPM " row_mask:0xf bank_mask:0xf\n\t"
#define PKB  " op_sel:[0,0,0] op_sel_hi:[1,0,1]\n\t"   /* bcast src1 word0 */

    // MAC block: 19 DPP broadcasts + 20 pk_fma over 4 chains, 3 t-bufs.
#define STEP_MAC() do {                                                       \
    asm volatile(                                                             \
  "v_mov_b32 v42, %[hA]\n\t"                                                  \
  "v_mov_b32_dpp v44, %[hA] row_ror:1"  DPPM                                  \
  "v_mov_b32_dpp v46, %[hA] row_ror:2"  DPPM                                  \
  "v_pk_fma_f32 %[P], %[w0], v[42:43], %[P]" PKB                              \
  "v_mov_b32_dpp v42, %[hA] row_ror:3"  DPPM                                  \
  "v_pk_fma_f32 %[Q], %[w1], v[44:45], %[Q]" PKB                              \
  "v_mov_b32_dpp v44, %[hA] row_ror:4"  DPPM                                  \
  "v_pk_fma_f32 %[R], %[w2], v[46:47], %[R]" PKB                              \
  "v_mov_b32_dpp v46, %[hA] row_ror:5"  DPPM                                  \
  "v_pk_fma_f32 %[Sc], %[w3], v[42:43], %[Sc]" PKB                            \
  "v_mov_b32_dpp v42, %[hA] row_ror:6"  DPPM                                  \
  "v_pk_fma_f32 %[P], %[w4], v[44:45], %[P]" PKB                              \
  "v_mov_b32_dpp v44, %[hA] row_ror:7"  DPPM                                  \
  "v_pk_fma_f32 %[Q], %[w5], v[46:47], %[Q]" PKB                              \
  "v_mov_b32_dpp v46, %[hA] row_ror:8"  DPPM                                  \
  "v_pk_fma_f32 %[R], %[w6], v[42:43], %[R]" PKB                              \
  "v_mov_b32_dpp v42, %[hA] row_ror:9"  DPPM                                  \
  "v_pk_fma_f32 %[Sc], %[w7], v[44:45], %[Sc]" PKB                            \
  "v_mov_b32_dpp v44, %[hA] row_ror:10" DPPM                                  \
  "v_pk_fma_f32 %[P], %[w8], v[46:47], %[P]" PKB                              \
  "v_mov_b32_dpp v46, %[hA] row_ror:11" DPPM                                  \
  "v_pk_fma_f32 %[Q], %[w9], v[42:43], %[Q]" PKB                              \
  "v_mov_b32_dpp v42, %[hA] row_ror:12" DPPM                                  \
  "v_pk_fma_f32 %[R], %[w10], v[44:45], %[R]" PKB                             \
  "v_mov_b32_dpp v44, %[hA] row_ror:13" DPPM                                  \
  "v_pk_fma_f32 %[Sc], %[w11], v[46:47], %[Sc]" PKB                           \
  "v_mov_b32_dpp v46, %[hA] row_ror:14" DPPM                                  \
  "v_pk_fma_f32 %[P], %[w12], v[42:43], %[P]" PKB                             \
  "v_mov_b32_dpp v42, %[hA] row_ror:15" DPPM                                  \
  "v_pk_fma_f32 %[Q], %[w13], v[44:45], %[Q]" PKB                             \
  "v_mov_b32_dpp v44, %[hB] quad_perm:[0,0,0,0]" DPPM                         \
  "v_pk_fma_f32 %[R], %[w14], v[46:47], %[R]" PKB                             \
  "v_mov_b32_dpp v46, %[hB] quad_perm:[1,1,1,1]" DPPM                         \
  "v_pk_fma_f32 %[Sc], %[w15], v[42:43], %[Sc]" PKB                           \
  "v_mov_b32_dpp v42, %[hB] quad_perm:[2,2,2,2]" DPPM                         \
  "v_pk_fma_f32 %[P], %[q0], v[44:45], %[P]" PKB                              \
  "v_mov_b32_dpp v44, %[hB] quad_perm:[3,3,3,3]" DPPM                         \
  "v_pk_fma_f32 %[Q], %[q1], v[46:47], %[Q]" PKB                              \
  "v_pk_fma_f32 %[R], %[q2], v[42:43], %[R]" PKB                              \
  "v_pk_fma_f32 %[Sc], %[q3], v[44:45], %[Sc]"                                \
  " op_sel:[0,0,0] op_sel_hi:[1,0,1]"                                         \
  : [P] "+v"(xiP), [Q] "+v"(xiQ), [R] "+v"(xiR), [Sc] "+v"(xiS)               \
  : [hA] "v"(hA), [hB] "v"(hB),                                               \
    [w0] "v"(w2[0]),   [w1] "v"(w2[1]),   [w2] "v"(w2[2]),   [w3] "v"(w2[3]), \
    [w4] "v"(w2[4]),   [w5] "v"(w2[5]),   [w6] "v"(w2[6]),   [w7] "v"(w2[7]), \
    [w8] "v"(w2[8]),   [w9] "v"(w2[9]),   [w10] "v"(w2[10]), [w11] "v"(w2[11]),\
    [w12] "v"(w2[12]), [w13] "v"(w2[13]), [w14] "v"(w2[14]), [w15] "v"(w2[15]),\
    [q0] "v"(wq2[0]),  [q1] "v"(wq2[1]),  [q2] "v"(wq2[2]),  [q3] "v"(wq2[3]) \
  : "v42","v43","v44","v45","v46","v47");                                     \
} while (0)

    // Tail block: combine + tanh, with next step's xi filling trans gaps.
#define STEP_TAIL(XV) do {                                                    \
    f32x2 xa_ = __builtin_shufflevector((XV), (XV), 0, 1);                    \
    f32x2 xb_ = __builtin_shufflevector((XV), (XV), 2, 3);                    \
    asm volatile(                                                             \
  "v_pk_add_f32 v[48:49], %[P], %[Q]\n\t"                                     \
  "v_pk_add_f32 v[50:51], %[R], %[Sc]\n\t"                                    \
  "v_pk_fma_f32 %[P], %[x0], %[xa], %[b2]" PKB                                \
  "v_pk_add_f32 v[48:49], v[48:49], v[50:51]\n\t"                             \
  "v_pk_mul_f32 %[Q], %[x1], %[xa] op_sel:[0,1] op_sel_hi:[1,1]\n\t"          \
  "v_pk_mul_f32 %[R], %[x2], %[xb] op_sel:[0,0] op_sel_hi:[1,0]\n\t"          \
  "v_exp_f32 v52, v48\n\t"                                                    \
  "v_exp_f32 v53, v49\n\t"                                                    \
  "v_pk_mul_f32 %[Sc], %[x3], %[xb] op_sel:[0,1] op_sel_hi:[1,1]\n\t"         \
  "v_add_f32 v52, 1.0, v52\n\t"                                               \
  "v_add_f32 v53, 1.0, v53\n\t"                                               \
  "v_rcp_f32 v52, v52\n\t"                                                    \
  "v_rcp_f32 v53, v53\n\t"                                                    \
  "v_fma_f32 %[hA], v52, -2.0, 1.0\n\t"                                       \
  "v_fma_f32 %[hB], v53, -2.0, 1.0"                                           \
  : [hA] "=v"(hA), [hB] "=v"(hB),                                             \
    [P] "+v"(xiP), [Q] "+v"(xiQ), [R] "+v"(xiR), [Sc] "+v"(xiS)               \
  : [xa] "v"(xa_), [xb] "v"(xb_),                                             \
    [x0] "v"(xiw[0]), [x1] "v"(xiw[1]), [x2] "v"(xiw[2]), [x3] "v"(xiw[3]),   \
    [b2] "v"(bias2)                                                           \
  : "v48","v49","v50","v51","v52","v53");                                     \
} while (0)

#define STEP(XV) do { STEP_MAC(); STEP_TAIL(XV); } while (0)

    // ---- prologue: stage block 0, compute xi(0), prime queue at x[1..3] ----
    xlds[0][e][j] = xp[j];                // lane j -> row j (coalesced)
    f32x4 x0v = xp[0];
    f32x2 xiP = f32x2{__builtin_fmaf(x0v[0], xiw[0][0], bias2[0]),
                      __builtin_fmaf(x0v[0], xiw[0][1], bias2[1])};
    f32x2 xiQ = f32x2{x0v[1] * xiw[1][0], x0v[1] * xiw[1][1]};
    f32x2 xiR = f32x2{x0v[2] * xiw[2][0], x0v[2] * xiw[2][1]};
    f32x2 xiS = f32x2{x0v[3] * xiw[3][0], x0v[3] * xiw[3][1]};
    f32x4 q0 = xlds[0][e][1];
    f32x4 q1 = xlds[0][e][2];
    f32x4 q2 = xlds[0][e][3];

    int cur = 0;
#pragma unroll 1
    for (int k = 0; k < NBLK; ++k) {
        const int kn = (k + 1 < NBLK) ? (k + 1) : (NBLK - 1);  // tail reload
        f32x4 xr = xp[kn * SB + j];       // global load at block TOP
        const int nxt = cur ^ 1;
#pragma unroll
        for (int s = 0; s < SB - 4; ++s) {                     // s = 0..11
            f32x4 xv = q0; q0 = q1; q1 = q2;
            q2 = xlds[cur][e][s + 4];     // 3-step LDS lookahead (shifted)
            STEP(xv);
        }
        xlds[nxt][e][j] = xr;             // prior reads of nxt already issued
        { f32x4 xv = q0; q0 = q1; q1 = q2; q2 = xlds[nxt][e][0]; STEP(xv); }
        { f32x4 xv = q0; q0 = q1; q1 = q2; q2 = xlds[nxt][e][1]; STEP(xv); }
        { f32x4 xv = q0; q0 = q1; q1 = q2; q2 = xlds[nxt][e][2]; STEP(xv); }
        { f32x4 xv = q0; q0 = q1; q1 = q2; q2 = xlds[nxt][e][3]; STEP(xv); }
        cur = nxt;
    }
#undef STEP
#undef STEP_MAC
#undef STEP_TAIL
#undef PKB
#undef DPPM

    // ---- epilogue: out[b][m] = fc_b[m] + sum_k h[k] * fc_w[m][k] ----
    hsh[e][j] = hA;                       // units 0..15
    if (j < 4) hsh[e][16 + j] = hB;       // lane j holds unit 16+j
    if (j < 4) {
        float o = fc_b[j];
#pragma unroll
        for (int kk = 0; kk < Hn; ++kk)
            o = __builtin_fmaf(hsh[e][kk], fc_w[j * Hn + kk], o);
        out[b * 4 + j] = o;
    }
}

extern "C" void kernel_launch(void* const* d_in, const int* in_sizes, int n_in,
                              void* d_out, int out_size, void* d_ws, size_t ws_size,
                              hipStream_t stream) {
    const float* x    = (const float*)d_in[0];
    const float* h0   = (const float*)d_in[1];
    const float* W_ih = (const float*)d_in[2];
    const float* W_hh = (const float*)d_in[3];
    const float* b_ih = (const float*)d_in[4];
    const float* b_hh = (const float*)d_in[5];
    const float* fc_w = (const float*)d_in[6];
    const float* fc_b = (const float*)d_in[7];
    float* out = (float*)d_out;

    // 4096 elements / 16 per block = 256 blocks = 1024 waves = 1 wave/SIMD.
    rnn_fwd<<<dim3(256), dim3(256), 0, stream>>>(x, h0, W_ih, W_hh, b_ih, b_hh,
                                                 fc_w, fc_b, out);
}